// Round 13
// baseline (175.785 us; speedup 1.0000x reference)
//
#include <hip/hip_runtime.h>
#include <hip/hip_fp16.h>
#include <cstdint>
#include <cstddef>

#define Bb 32
#define Ss 2048
#define Ee 1024
#define Qq 1024
#define Aa 512

typedef _Float16 half8 __attribute__((ext_vector_type(8)));
typedef float f32x4 __attribute__((ext_vector_type(4)));

// ---- workspace byte offsets ----
#define WS_PROJQ 0u          // 32*512 f32      = 65536 B
#define WS_MPART 65536u      // 32*32 f32       = 4096 B
#define WS_LPART 69632u      // 32*32 f32       = 4096 B
#define WS_CTXP  73728u      // 32*32*512 f32   = 2097152 B
#define WS_WWS   2170880u    // 1024*512 f16    = 1048576 B

__device__ __forceinline__ float fast_tanh(float x) {
  float e = __expf(2.0f * x);
  return 1.0f - __fdividef(2.0f, e + 1.0f);
}

#define MFMA16(d, a8, b8) d = __builtin_amdgcn_mfma_f32_16x16x32_f16(a8, b8, d, 0, 0, 0)

// ---- W_in fp32 [E][A] -> fp16 tiled [kt32][ks4][a512][8]  (1 MB, L2-resident)
__global__ void k_convw(const float* __restrict__ win, _Float16* __restrict__ wws) {
  int gid = blockIdx.x * 256 + threadIdx.x;
  int a  = gid & 511;
  int ks = (gid >> 9) & 3;
  int kt = gid >> 11;
  int k0 = kt * 32 + ks * 8;
  half8 v;
  #pragma unroll
  for (int j = 0; j < 8; ++j) v[j] = (_Float16)win[(size_t)(k0 + j) * Aa + a];
  *(half8*)(wws + ((size_t)kt * 16384 + (size_t)ks * 4096 + (size_t)a * 8)) = v;
}

// ---- proj_q[b][a]
__global__ void k_projq(const float* __restrict__ query, const float* __restrict__ wq,
                        float* __restrict__ projq) {
  __shared__ float red[256];
  int b  = blockIdx.y;
  int al = threadIdx.x & 63;
  int eq = threadIdx.x >> 6;
  int a  = blockIdx.x * 64 + al;
  const float* q = query + (size_t)b * Qq;
  float s = 0.f;
  int e0 = eq * 256;
  #pragma unroll 4
  for (int e = e0; e < e0 + 256; ++e)
    s += q[e] * wq[(size_t)e * Aa + a];
  red[threadIdx.x] = s;
  __syncthreads();
  if (eq == 0)
    projq[(size_t)b * Aa + a] = red[al] + red[al + 64] + red[al + 128] + red[al + 192];
}

// ---- main: BM=64 x BN=512, K_STEP=64 (16 tiles), 512 thr / 8 waves.
// Wave w owns ALL 64 rows x cols [w*64, w*64+64)  (B-read amp = 1).
// Per tile: 4 phases of {ds_read subtile, 8 MFMA}; staging issued ph0;
// A-cvt at ph3 = counted vmcnt drain (covers B gloads, issued 3 phases prior);
// ONE raw s_barrier per tile (after per-wave lgkmcnt(0)).
__global__ __launch_bounds__(512, 2)
void k_main(const float* __restrict__ inp, const _Float16* __restrict__ wws,
            const float* __restrict__ projq, const float* __restrict__ watt,
            float* __restrict__ mpart, float* __restrict__ lpart,
            float* __restrict__ ctxp)
{
  __shared__ __align__(16) char pool[147456];     // 16K A-dbuf | 128K B-dbuf
  _Float16* AldsB = (_Float16*)pool;              // [p][kq8][row64][8], p stride 4096 halfs
  _Float16* BldsB = (_Float16*)(pool + 16384);    // [p][khkb8][col512][8], p stride 32768 halfs

  const int tid = threadIdx.x;
  const int l   = tid & 63;
  const int w   = tid >> 6;        // wave 0..7 = col-slice (cols w*64..+63)
  const int lr  = l & 15;
  const int kb  = l >> 4;          // k-slot 0..3
  const int b   = blockIdx.y;
  const int ch  = blockIdx.x;      // s-chunk of 64 rows, 0..31

  // A staging: thread t -> row = t>>3 (0..63), akq = t&7 (8-f32 k-group)
  const int arow = tid >> 3;
  const int akq  = tid & 7;
  const float* asrc = inp + ((size_t)(b * Ss + ch * 64 + arow)) * Ee + akq * 8;
  const int awoff = (akq * 64 + arow) * 8;        // halfs: [akq][row][8]

  // B staging: 8 x 16B per thread per tile, linear
  const char* bsrc0 = (const char*)wws + (size_t)tid * 16;

  f32x4 acc[4][4];
  #pragma unroll
  for (int m = 0; m < 4; ++m)
    #pragma unroll
    for (int n = 0; n < 4; ++n) acc[m][n] = (f32x4){0.f, 0.f, 0.f, 0.f};

  // ---- prologue: stage tile 0 into buf 0
  {
    #pragma unroll
    for (int i = 0; i < 8; ++i)
      __builtin_amdgcn_global_load_lds(
        (const __attribute__((address_space(1))) void*)(bsrc0 + i * 8192),
        (__attribute__((address_space(3))) void*)(pool + 16384 + tid * 16 + i * 8192),
        16, 0, 0);
    float4 x0 = *(const float4*)(asrc);
    float4 x1 = *(const float4*)(asrc + 4);
    half8 h;
    h[0]=(_Float16)x0.x; h[1]=(_Float16)x0.y; h[2]=(_Float16)x0.z; h[3]=(_Float16)x0.w;
    h[4]=(_Float16)x1.x; h[5]=(_Float16)x1.y; h[6]=(_Float16)x1.z; h[7]=(_Float16)x1.w;
    *(half8*)(AldsB + awoff) = h;
  }
  __syncthreads();

  int pp = 0;
  for (int t = 0; t < 16; ++t) {
    const _Float16* Abase = AldsB + pp * 4096;
    const _Float16* Bbase = BldsB + pp * 32768;

    // ---- phase 0: kh0 — B frags + A mf0,1; issue next-tile staging
    half8 bf0 = *(const half8*)(Bbase + (kb * 512 + w * 64      + lr) * 8);
    half8 bf1 = *(const half8*)(Bbase + (kb * 512 + w * 64 + 16 + lr) * 8);
    half8 bf2 = *(const half8*)(Bbase + (kb * 512 + w * 64 + 32 + lr) * 8);
    half8 bf3 = *(const half8*)(Bbase + (kb * 512 + w * 64 + 48 + lr) * 8);
    half8 af0 = *(const half8*)(Abase + (kb * 64      + lr) * 8);
    half8 af1 = *(const half8*)(Abase + (kb * 64 + 16 + lr) * 8);

    float4 aL0, aL1;
    if (t < 15) {
      const char* bs = bsrc0 + (size_t)(t + 1) * 65536;
      #pragma unroll
      for (int i = 0; i < 8; ++i)
        __builtin_amdgcn_global_load_lds(
          (const __attribute__((address_space(1))) void*)(bs + i * 8192),
          (__attribute__((address_space(3))) void*)(pool + 16384 + (pp ^ 1) * 65536 + tid * 16 + i * 8192),
          16, 0, 0);
      __builtin_amdgcn_sched_barrier(0);          // B gloads BEFORE A loads (vmcnt order)
      const float* ap = asrc + (size_t)(t + 1) * 64;
      aL0 = *(const float4*)(ap);
      aL1 = *(const float4*)(ap + 4);
      __builtin_amdgcn_sched_barrier(0);
    }

    __builtin_amdgcn_s_setprio(1);
    MFMA16(acc[0][0], af0, bf0); MFMA16(acc[0][1], af0, bf1);
    MFMA16(acc[0][2], af0, bf2); MFMA16(acc[0][3], af0, bf3);
    MFMA16(acc[1][0], af1, bf0); MFMA16(acc[1][1], af1, bf1);
    MFMA16(acc[1][2], af1, bf2); MFMA16(acc[1][3], af1, bf3);
    __builtin_amdgcn_s_setprio(0);

    // ---- phase 1: kh0 — A mf2,3
    half8 af2 = *(const half8*)(Abase + (kb * 64 + 32 + lr) * 8);
    half8 af3 = *(const half8*)(Abase + (kb * 64 + 48 + lr) * 8);
    __builtin_amdgcn_s_setprio(1);
    MFMA16(acc[2][0], af2, bf0); MFMA16(acc[2][1], af2, bf1);
    MFMA16(acc[2][2], af2, bf2); MFMA16(acc[2][3], af2, bf3);
    MFMA16(acc[3][0], af3, bf0); MFMA16(acc[3][1], af3, bf1);
    MFMA16(acc[3][2], af3, bf2); MFMA16(acc[3][3], af3, bf3);
    __builtin_amdgcn_s_setprio(0);

    // ---- phase 2: kh1 — B frags + A mf0,1
    bf0 = *(const half8*)(Bbase + ((4 + kb) * 512 + w * 64      + lr) * 8);
    bf1 = *(const half8*)(Bbase + ((4 + kb) * 512 + w * 64 + 16 + lr) * 8);
    bf2 = *(const half8*)(Bbase + ((4 + kb) * 512 + w * 64 + 32 + lr) * 8);
    bf3 = *(const half8*)(Bbase + ((4 + kb) * 512 + w * 64 + 48 + lr) * 8);
    af0 = *(const half8*)(Abase + ((4 + kb) * 64      + lr) * 8);
    af1 = *(const half8*)(Abase + ((4 + kb) * 64 + 16 + lr) * 8);
    __builtin_amdgcn_s_setprio(1);
    MFMA16(acc[0][0], af0, bf0); MFMA16(acc[0][1], af0, bf1);
    MFMA16(acc[0][2], af0, bf2); MFMA16(acc[0][3], af0, bf3);
    MFMA16(acc[1][0], af1, bf0); MFMA16(acc[1][1], af1, bf1);
    MFMA16(acc[1][2], af1, bf2); MFMA16(acc[1][3], af1, bf3);
    __builtin_amdgcn_s_setprio(0);

    // ---- phase 3: kh1 — A mf2,3; A-cvt (counted vmcnt drain) + ds_write; tile barrier
    af2 = *(const half8*)(Abase + ((4 + kb) * 64 + 32 + lr) * 8);
    af3 = *(const half8*)(Abase + ((4 + kb) * 64 + 48 + lr) * 8);
    if (t < 15) {
      __builtin_amdgcn_sched_barrier(0);
      half8 h;                                    // use of aL waits vmcnt -> drains B gloads too
      h[0]=(_Float16)aL0.x; h[1]=(_Float16)aL0.y; h[2]=(_Float16)aL0.z; h[3]=(_Float16)aL0.w;
      h[4]=(_Float16)aL1.x; h[5]=(_Float16)aL1.y; h[6]=(_Float16)aL1.z; h[7]=(_Float16)aL1.w;
      *(half8*)(AldsB + (pp ^ 1) * 4096 + awoff) = h;
      __builtin_amdgcn_sched_barrier(0);
    }
    __builtin_amdgcn_s_setprio(1);
    MFMA16(acc[2][0], af2, bf0); MFMA16(acc[2][1], af2, bf1);
    MFMA16(acc[2][2], af2, bf2); MFMA16(acc[2][3], af2, bf3);
    MFMA16(acc[3][0], af3, bf0); MFMA16(acc[3][1], af3, bf1);
    MFMA16(acc[3][2], af3, bf2); MFMA16(acc[3][3], af3, bf3);
    __builtin_amdgcn_s_setprio(0);

    if (t < 15) {
      asm volatile("s_waitcnt lgkmcnt(0)" ::: "memory");   // own ds_write visible
      __builtin_amdgcn_sched_barrier(0);
      __builtin_amdgcn_s_barrier();                        // raw: no vmcnt(0) drain
      __builtin_amdgcn_sched_barrier(0);
    }
    pp ^= 1;
  }

  // ---------------- epilogue ----------------
  __syncthreads();                       // all K-loop LDS traffic done; overlay pool
  float* pq_s = (float*)pool;                      // 2 KB
  float* wa_s = (float*)(pool + 2048);             // 2 KB
  float (*sc8)[8] = (float(*)[8])(pool + 4096);    // 64x8 f32 = 2 KB
  float* pbuf = (float*)(pool + 6144);             // 256 B

  pq_s[tid] = projq[(size_t)b * Aa + tid];
  wa_s[tid] = watt[tid];
  __syncthreads();

  // C/D: col = lane&15 (within 16-frag), frag row = kb*4 + j
  // wave cols: w*64 + nf*16 + lr ; rows: mf*16 + kb*4 + j
  float sp[4][4];
  #pragma unroll
  for (int m = 0; m < 4; ++m)
    #pragma unroll
    for (int j = 0; j < 4; ++j) sp[m][j] = 0.f;

  #pragma unroll
  for (int n = 0; n < 4; ++n) {
    int col = w * 64 + n * 16 + lr;
    float wan = wa_s[col], pqn = pq_s[col];
    #pragma unroll
    for (int m = 0; m < 4; ++m)
      #pragma unroll
      for (int j = 0; j < 4; ++j)
        sp[m][j] += fast_tanh(acc[m][n][j] + pqn) * wan;
  }
  #pragma unroll
  for (int m = 0; m < 4; ++m)
    #pragma unroll
    for (int j = 0; j < 4; ++j) {
      float v = sp[m][j];
      v += __shfl_xor(v, 1);
      v += __shfl_xor(v, 2);
      v += __shfl_xor(v, 4);
      v += __shfl_xor(v, 8);
      sp[m][j] = v;                      // sum over this wave's 16-col group (lr)
    }
  if (lr == 0) {
    #pragma unroll
    for (int m = 0; m < 4; ++m)
      #pragma unroll
      for (int j = 0; j < 4; ++j)
        sc8[m * 16 + kb * 4 + j][w] = sp[m][j];
  }
  __syncthreads();

  const int pi = b * 32 + ch;
  if (tid < 64) {
    float s = 0.f;
    #pragma unroll
    for (int q = 0; q < 8; ++q) s += sc8[tid][q];
    float mx = s;
    #pragma unroll
    for (int off = 1; off < 64; off <<= 1) mx = fmaxf(mx, __shfl_xor(mx, off));
    float pe = __expf(s - mx);
    float ls = pe;
    #pragma unroll
    for (int off = 1; off < 64; off <<= 1) ls += __shfl_xor(ls, off);
    pbuf[tid] = pe;
    if (tid == 0) { mpart[pi] = mx; lpart[pi] = ls; }
  }
  __syncthreads();

  // ctx partial: per lane per nf, sum over mf,j then over kb (shfl 16/32)
  float cv[4];
  #pragma unroll
  for (int n = 0; n < 4; ++n) cv[n] = 0.f;
  #pragma unroll
  for (int m = 0; m < 4; ++m)
    #pragma unroll
    for (int j = 0; j < 4; ++j) {
      float pw = pbuf[m * 16 + kb * 4 + j];
      #pragma unroll
      for (int n = 0; n < 4; ++n) cv[n] += pw * acc[m][n][j];
    }
  #pragma unroll
  for (int n = 0; n < 4; ++n) {
    float v = cv[n];
    v += __shfl_xor(v, 16);
    v += __shfl_xor(v, 32);
    cv[n] = v;                           // summed over kb -> all 64 rows
  }
  if (l < 16) {
    #pragma unroll
    for (int n = 0; n < 4; ++n)
      ctxp[(size_t)pi * 512 + w * 64 + n * 16 + l] = cv[n];
  }
}

// ---- merge 32 chunk partials per batch (flash-style combine)
__global__ void k_comb(const float* __restrict__ mpart, const float* __restrict__ lpart,
                       const float* __restrict__ ctxp, float* __restrict__ out) {
  int b = blockIdx.x, a = threadIdx.x;
  float Mg = -1e30f;
  #pragma unroll 8
  for (int i = 0; i < 32; ++i) Mg = fmaxf(Mg, mpart[b * 32 + i]);
  float den = 0.f, s = 0.f;
  #pragma unroll 8
  for (int i = 0; i < 32; ++i) {
    float e = __expf(mpart[b * 32 + i] - Mg);
    den += lpart[b * 32 + i] * e;
    s   += ctxp[((size_t)(b * 32 + i)) * 512 + a] * e;
  }
  out[(size_t)b * 512 + a] = s / den;
}

extern "C" void kernel_launch(void* const* d_in, const int* in_sizes, int n_in,
                              void* d_out, int out_size, void* d_ws, size_t ws_size,
                              hipStream_t stream) {
  const float* inputs = (const float*)d_in[0];
  const float* query  = (const float*)d_in[1];
  const float* W_in   = (const float*)d_in[2];
  const float* W_q    = (const float*)d_in[3];
  const float* w_att  = (const float*)d_in[4];
  float* out = (float*)d_out;

  char* ws = (char*)d_ws;
  float*    projq = (float*)(ws + WS_PROJQ);
  float*    mpart = (float*)(ws + WS_MPART);
  float*    lpart = (float*)(ws + WS_LPART);
  float*    ctxp  = (float*)(ws + WS_CTXP);
  _Float16* wws   = (_Float16*)(ws + WS_WWS);

  k_convw<<<256, 256, 0, stream>>>(W_in, wws);
  k_projq<<<dim3(8, 32), 256, 0, stream>>>(query, W_q, projq);
  k_main<<<dim3(32, 32), 512, 0, stream>>>(inputs, wws, projq, w_att, mpart, lpart, ctxp);
  k_comb<<<32, 512, 0, stream>>>(mpart, lpart, ctxp, out);
}

// Round 14
// 158.189 us; speedup vs baseline: 1.1112x; 1.1112x over previous
//
#include <hip/hip_runtime.h>
#include <hip/hip_fp16.h>
#include <cstdint>
#include <cstddef>

#define Bb 32
#define Ss 2048
#define Ee 1024
#define Qq 1024
#define Aa 512

typedef _Float16 half8 __attribute__((ext_vector_type(8)));
typedef _Float16 half4 __attribute__((ext_vector_type(4)));
typedef float f32x16 __attribute__((ext_vector_type(16)));

// ---- workspace byte offsets ----
#define WS_PROJQ 0u          // 32*512 f32      = 65536 B
#define WS_MPART 65536u      // 32*32 f32       = 4096 B
#define WS_LPART 69632u      // 32*32 f32       = 4096 B
#define WS_CTXP  73728u      // 32*32*512 f32   = 2097152 B
#define WS_WWS   2170880u    // 1024*512 f16    = 1048576 B

__device__ __forceinline__ float fast_tanh(float x) {
  float e = __expf(2.0f * x);
  return 1.0f - __fdividef(2.0f, e + 1.0f);
}

#define MFMA32(d, a8, b8) d = __builtin_amdgcn_mfma_f32_32x32x16_f16(a8, b8, d, 0, 0, 0)

// ---- W_in fp32 [E][A] -> fp16 tiled [kt32][h4][a512][8]  (1 MB, L2-resident)
__global__ void k_convw(const float* __restrict__ win, _Float16* __restrict__ wws) {
  int gid = blockIdx.x * 256 + threadIdx.x;
  int a  = gid & 511;
  int ks = (gid >> 9) & 3;
  int kt = gid >> 11;
  int k0 = kt * 32 + ks * 8;
  half8 v;
  #pragma unroll
  for (int j = 0; j < 8; ++j) v[j] = (_Float16)win[(size_t)(k0 + j) * Aa + a];
  *(half8*)(wws + ((size_t)kt * 16384 + (size_t)ks * 4096 + (size_t)a * 8)) = v;
}

// ---- proj_q[b][a]
__global__ void k_projq(const float* __restrict__ query, const float* __restrict__ wq,
                        float* __restrict__ projq) {
  __shared__ float red[256];
  int b  = blockIdx.y;
  int al = threadIdx.x & 63;
  int eq = threadIdx.x >> 6;
  int a  = blockIdx.x * 64 + al;
  const float* q = query + (size_t)b * Qq;
  float s = 0.f;
  int e0 = eq * 256;
  #pragma unroll 4
  for (int e = e0; e < e0 + 256; ++e)
    s += q[e] * wq[(size_t)e * Aa + a];
  red[threadIdx.x] = s;
  __syncthreads();
  if (eq == 0)
    projq[(size_t)b * Aa + a] = red[al] + red[al + 64] + red[al + 128] + red[al + 192];
}

// ---- main: BM=64 x BN=512, BK=32, 512 thr / 8 waves, 32x32x16 MFMA.
// Wave w owns all 64 rows x cols [w*64, w*64+64): acc[2][2] f32x16 = 64 regs.
// Per wave-kt: 8 ds_read_b128 + 8 MFMA (vs 10+16 at 16x16) -> better pipe ratio.
// A: reg-staged f32->f16 depth-2 (R8/R11-verified). B: 4x global_load_lds-16.
// LDS 72 KB -> 2 blocks/CU. Plain __syncthreads per kt (best-timed R8 skeleton).
__global__ __launch_bounds__(512, 4)
void k_main(const float* __restrict__ inp, const _Float16* __restrict__ wws,
            const float* __restrict__ projq, const float* __restrict__ watt,
            float* __restrict__ mpart, float* __restrict__ lpart,
            float* __restrict__ ctxp)
{
  __shared__ __align__(16) char pool[73728];     // 8K A-dbuf | 64K B-dbuf; epilogue overlays
  _Float16* AldsB = (_Float16*)pool;             // [p][h4][row64][8], p stride 2048 halfs
  _Float16* BldsB = (_Float16*)(pool + 8192);    // [p][h4][col512][8], p stride 16384 halfs

  const int tid = threadIdx.x;
  const int l   = tid & 63;
  const int w   = tid >> 6;        // wave 0..7 = col-slice (cols w*64..+63)
  const int lh  = l & 31;          // row/col within 32-frag
  const int hi  = l >> 5;          // k-half selector
  const int b   = blockIdx.y;
  const int ch  = blockIdx.x;      // s-chunk of 64 rows, 0..31

  // A staging: thread t -> row = t>>3 (0..63), kq = t&7 (4-f32 group)
  const int arow = tid >> 3;
  const int kq   = tid & 7;
  const float* asrc = inp + ((size_t)(b * Ss + ch * 64 + arow)) * Ee + kq * 4;
  const int awoff = ((kq >> 1) * 64 + arow) * 8 + (kq & 1) * 4;   // f16 elem offset

  // B staging: 4 x 16B per thread per kt, linear
  const char* bsrc0 = (const char*)wws + (size_t)tid * 16;

  f32x16 acc[2][2];
  #pragma unroll
  for (int m = 0; m < 2; ++m)
    #pragma unroll
    for (int n = 0; n < 2; ++n)
      #pragma unroll
      for (int r = 0; r < 16; ++r) acc[m][n][r] = 0.f;

  // ---- prologue: stage kt=0 into buf 0; preload A(1)
  {
    float4 x = *(const float4*)(asrc);
    half4 h; h[0]=(_Float16)x.x; h[1]=(_Float16)x.y; h[2]=(_Float16)x.z; h[3]=(_Float16)x.w;
    *(half4*)(AldsB + awoff) = h;
    #pragma unroll
    for (int i = 0; i < 4; ++i)
      __builtin_amdgcn_global_load_lds(
        (const __attribute__((address_space(1))) void*)(bsrc0 + i * 8192),
        (__attribute__((address_space(3))) void*)(pool + 8192 + tid * 16 + i * 8192),
        16, 0, 0);
  }
  float4 areg = *(const float4*)(asrc + 32);     // A(1)
  __syncthreads();

  int p = 0;
  for (int kt = 0; kt < 32; ++kt) {
    // 1) issue B(kt+1) gloads into p^1
    if (kt < 31) {
      const char* bs = bsrc0 + (size_t)(kt + 1) * 32768;
      #pragma unroll
      for (int i = 0; i < 4; ++i)
        __builtin_amdgcn_global_load_lds(
          (const __attribute__((address_space(1))) void*)(bs + i * 8192),
          (__attribute__((address_space(3))) void*)(pool + 8192 + (p ^ 1) * 32768 + tid * 16 + i * 8192),
          16, 0, 0);
    }
    // 2) A(kt+2) prefetch (consumed next iter)
    const int ktn2 = (kt < 30) ? kt + 2 : 31;
    float4 anext = *(const float4*)(asrc + (size_t)ktn2 * 32);

    // 3) fragments(kt) + 8 MFMA  — frag k-layout: row/col=l&31, k=(l>>5)*8+j
    const _Float16* Ap = AldsB + p * 2048;
    const _Float16* Bp = BldsB + p * 16384;
    {
      // ks = 0 : h-group = hi
      half8 af0 = *(const half8*)(Ap + ((hi) * 64 +      lh) * 8);
      half8 af1 = *(const half8*)(Ap + ((hi) * 64 + 32 + lh) * 8);
      half8 bf0 = *(const half8*)(Bp + ((hi) * 512 + w * 64 +      lh) * 8);
      half8 bf1 = *(const half8*)(Bp + ((hi) * 512 + w * 64 + 32 + lh) * 8);
      MFMA32(acc[0][0], af0, bf0); MFMA32(acc[0][1], af0, bf1);
      MFMA32(acc[1][0], af1, bf0); MFMA32(acc[1][1], af1, bf1);
    }
    {
      // ks = 1 : h-group = 2 + hi
      half8 af0 = *(const half8*)(Ap + ((2 + hi) * 64 +      lh) * 8);
      half8 af1 = *(const half8*)(Ap + ((2 + hi) * 64 + 32 + lh) * 8);
      half8 bf0 = *(const half8*)(Bp + ((2 + hi) * 512 + w * 64 +      lh) * 8);
      half8 bf1 = *(const half8*)(Bp + ((2 + hi) * 512 + w * 64 + 32 + lh) * 8);
      MFMA32(acc[0][0], af0, bf0); MFMA32(acc[0][1], af0, bf1);
      MFMA32(acc[1][0], af1, bf0); MFMA32(acc[1][1], af1, bf1);
    }

    // 4) write A(kt+1) (loaded LAST iteration) into p^1
    if (kt < 31) {
      half4 h; h[0]=(_Float16)areg.x; h[1]=(_Float16)areg.y; h[2]=(_Float16)areg.z; h[3]=(_Float16)areg.w;
      *(half4*)(AldsB + (p ^ 1) * 2048 + awoff) = h;
    }
    __syncthreads();
    p ^= 1;
    areg = anext;
  }

  // ---------------- epilogue (32x32 C/D: col=l&31, row=(r&3)+8*(r>>2)+4*hi) ----------------
  __syncthreads();                       // overlay pool
  float* pq_s = (float*)pool;                      // 2 KB
  float* wa_s = (float*)(pool + 2048);             // 2 KB
  float (*sc8)[8] = (float(*)[8])(pool + 4096);    // 64x8 f32 = 2 KB
  float* pbuf = (float*)(pool + 6144);             // 256 B

  pq_s[tid] = projq[(size_t)b * Aa + tid];
  wa_s[tid] = watt[tid];
  __syncthreads();

  const float pq0 = pq_s[w * 64 +      lh], wa0 = wa_s[w * 64 +      lh];
  const float pq1 = pq_s[w * 64 + 32 + lh], wa1 = wa_s[w * 64 + 32 + lh];

  // score partials: per (m, reg) sum over this lane's 2 cols, then over the 32 cols (lh)
  #pragma unroll
  for (int m = 0; m < 2; ++m)
    #pragma unroll
    for (int r = 0; r < 16; ++r) {
      float v = fast_tanh(acc[m][0][r] + pq0) * wa0 + fast_tanh(acc[m][1][r] + pq1) * wa1;
      v += __shfl_xor(v, 1);
      v += __shfl_xor(v, 2);
      v += __shfl_xor(v, 4);
      v += __shfl_xor(v, 8);
      v += __shfl_xor(v, 16);
      if (lh == 0)
        sc8[m * 32 + (r & 3) + 8 * (r >> 2) + 4 * hi][w] = v;
    }
  __syncthreads();

  const int pi = b * 32 + ch;
  if (tid < 64) {
    float s = 0.f;
    #pragma unroll
    for (int q = 0; q < 8; ++q) s += sc8[tid][q];
    float mx = s;
    #pragma unroll
    for (int off = 1; off < 64; off <<= 1) mx = fmaxf(mx, __shfl_xor(mx, off));
    float pe = __expf(s - mx);
    float ls = pe;
    #pragma unroll
    for (int off = 1; off < 64; off <<= 1) ls += __shfl_xor(ls, off);
    pbuf[tid] = pe;
    if (tid == 0) { mpart[pi] = mx; lpart[pi] = ls; }
  }
  __syncthreads();

  // ctx partial: cv[n] = sum over rows of p[row]*proj[row][col]; lane l and l^32
  // together cover all 32 rows of each m-frag -> one shfl_xor(32) completes the sum.
  float cv0 = 0.f, cv1 = 0.f;
  #pragma unroll
  for (int m = 0; m < 2; ++m)
    #pragma unroll
    for (int r = 0; r < 16; ++r) {
      float pw = pbuf[m * 32 + (r & 3) + 8 * (r >> 2) + 4 * hi];
      cv0 += pw * acc[m][0][r];
      cv1 += pw * acc[m][1][r];
    }
  cv0 += __shfl_xor(cv0, 32);
  cv1 += __shfl_xor(cv1, 32);
  if (l < 32) {
    ctxp[(size_t)pi * 512 + w * 64 +      l] = cv0;
    ctxp[(size_t)pi * 512 + w * 64 + 32 + l] = cv1;
  }
}

// ---- merge 32 chunk partials per batch (flash-style combine)
__global__ void k_comb(const float* __restrict__ mpart, const float* __restrict__ lpart,
                       const float* __restrict__ ctxp, float* __restrict__ out) {
  int b = blockIdx.x, a = threadIdx.x;
  float Mg = -1e30f;
  #pragma unroll 8
  for (int i = 0; i < 32; ++i) Mg = fmaxf(Mg, mpart[b * 32 + i]);
  float den = 0.f, s = 0.f;
  #pragma unroll 8
  for (int i = 0; i < 32; ++i) {
    float e = __expf(mpart[b * 32 + i] - Mg);
    den += lpart[b * 32 + i] * e;
    s   += ctxp[((size_t)(b * 32 + i)) * 512 + a] * e;
  }
  out[(size_t)b * 512 + a] = s / den;
}

extern "C" void kernel_launch(void* const* d_in, const int* in_sizes, int n_in,
                              void* d_out, int out_size, void* d_ws, size_t ws_size,
                              hipStream_t stream) {
  const float* inputs = (const float*)d_in[0];
  const float* query  = (const float*)d_in[1];
  const float* W_in   = (const float*)d_in[2];
  const float* W_q    = (const float*)d_in[3];
  const float* w_att  = (const float*)d_in[4];
  float* out = (float*)d_out;

  char* ws = (char*)d_ws;
  float*    projq = (float*)(ws + WS_PROJQ);
  float*    mpart = (float*)(ws + WS_MPART);
  float*    lpart = (float*)(ws + WS_LPART);
  float*    ctxp  = (float*)(ws + WS_CTXP);
  _Float16* wws   = (_Float16*)(ws + WS_WWS);

  k_convw<<<256, 256, 0, stream>>>(W_in, wws);
  k_projq<<<dim3(8, 32), 256, 0, stream>>>(query, W_q, projq);
  k_main<<<dim3(32, 32), 512, 0, stream>>>(inputs, wws, projq, w_att, mpart, lpart, ctxp);
  k_comb<<<32, 512, 0, stream>>>(mpart, lpart, ctxp, out);
}

// Round 16
// 137.183 us; speedup vs baseline: 1.2814x; 1.1531x over previous
//
#include <hip/hip_runtime.h>
#include <hip/hip_fp16.h>
#include <cstdint>
#include <cstddef>

#define Bb 32
#define Ss 2048
#define Ee 1024
#define Qq 1024
#define Aa 512

typedef _Float16 half8 __attribute__((ext_vector_type(8)));
typedef _Float16 half4 __attribute__((ext_vector_type(4)));
typedef __fp16 fp16x2 __attribute__((ext_vector_type(2)));
typedef float f32x4 __attribute__((ext_vector_type(4)));

// ---- workspace byte offsets ----
#define WS_PROJQ 0u          // 32*512 f32      = 65536 B
#define WS_MPART 65536u      // 32*16 f32       = 2048 B
#define WS_LPART 67584u      // 32*16 f32       = 2048 B
#define WS_CTXP  69632u      // 32*16*512 f32   = 1048576 B
#define WS_WWS   1118208u    // 1024*512 f16    = 1048576 B

__device__ __forceinline__ float fast_tanh(float x) {
  float e = __expf(2.0f * x);
  return 1.0f - __fdividef(2.0f, e + 1.0f);
}

// packed f32x2 -> f16x2 convert (1 VALU op each) — cuts staging VALU ~3x vs scalar cvt
__device__ __forceinline__ half4 cvt4(float4 x) {
  fp16x2 lo = __builtin_amdgcn_cvt_pkrtz(x.x, x.y);
  fp16x2 hi = __builtin_amdgcn_cvt_pkrtz(x.z, x.w);
  half4 r;
  r[0] = (_Float16)lo[0]; r[1] = (_Float16)lo[1];
  r[2] = (_Float16)hi[0]; r[3] = (_Float16)hi[1];
  return r;
}

// ---- W_in fp32 [E][A] -> fp16 tiled [kt][ks][a][8]  (1 MB, L2-resident)
__global__ void k_convw(const float* __restrict__ win, _Float16* __restrict__ wws) {
  int gid = blockIdx.x * 256 + threadIdx.x;
  int a  = gid & 511;
  int ks = (gid >> 9) & 3;
  int kt = gid >> 11;
  int k0 = kt * 32 + ks * 8;
  half8 v;
  #pragma unroll
  for (int j = 0; j < 8; ++j) v[j] = (_Float16)win[(size_t)(k0 + j) * Aa + a];
  *(half8*)(wws + ((size_t)kt * 16384 + (size_t)ks * 4096 + (size_t)a * 8)) = v;
}

// ---- proj_q[b][a]
__global__ void k_projq(const float* __restrict__ query, const float* __restrict__ wq,
                        float* __restrict__ projq) {
  __shared__ float red[256];
  int b  = blockIdx.y;
  int al = threadIdx.x & 63;
  int eq = threadIdx.x >> 6;
  int a  = blockIdx.x * 64 + al;
  const float* q = query + (size_t)b * Qq;
  float s = 0.f;
  int e0 = eq * 256;
  #pragma unroll 4
  for (int e = e0; e < e0 + 256; ++e)
    s += q[e] * wq[(size_t)e * Aa + a];
  red[threadIdx.x] = s;
  __syncthreads();
  if (eq == 0)
    projq[(size_t)b * Aa + a] = red[al] + red[al + 64] + red[al + 128] + red[al + 192];
}

// ---- main: R8 verbatim (best-known: BM=128 x BN=512, BK=32, 1024 thr, 16 waves)
// with packed cvt_pkrtz A-convert (only delta vs R8).
__global__ __launch_bounds__(1024, 4)
void k_main(const float* __restrict__ inp, const _Float16* __restrict__ wws,
            const float* __restrict__ projq, const float* __restrict__ watt,
            float* __restrict__ mpart, float* __restrict__ lpart,
            float* __restrict__ ctxp)
{
  __shared__ __align__(16) _Float16 Alds[2][4 * 128 * 8];   // [p][ks][row128][8] 2x8KB
  __shared__ __align__(16) _Float16 Blds[2][4 * 512 * 8];   // [p][ks][a][8]      2x32KB
  __shared__ float pq_s[512];
  __shared__ float wa_s[512];
  __shared__ float sc4[128][4];
  __shared__ float pbuf[128];
  __shared__ float red2[8];
  __shared__ float ctx2[4][512];

  const int tid = threadIdx.x;
  const int l   = tid & 63;
  const int w   = tid >> 6;        // wave 0..15
  const int lr  = l & 15;
  const int kb  = l >> 4;          // k-slot 0..3
  const int wr  = w >> 2;          // m-quarter 0..3 (rows wr*32..+31)
  const int wc  = w & 3;           // n-slice 0..3 (cols wc*128..+127)
  const int b   = blockIdx.y;
  const int ch  = blockIdx.x;      // s-chunk of 128 rows, 0..15

  if (tid < 512) {
    pq_s[tid] = projq[(size_t)b * Aa + tid];
    wa_s[tid] = watt[tid];
  }

  // A staging: thread t -> row = t>>3 (0..127), kq = t&7 (float4 group)
  const int arow = tid >> 3;
  const int kq   = tid & 7;
  const float* asrc = inp + ((size_t)(b * Ss + ch * 128 + arow)) * Ee + kq * 4;
  const int awoff = ((kq >> 1) * 128 + arow) * 8 + (kq & 1) * 4;   // f16 elem offset

  // B staging: 2 x 16B per thread, linear (tid*16 + i*16384 covers 32KB/kt)
  const char* bsrc0 = (const char*)wws + (size_t)tid * 16;

  f32x4 acc[2][8];
  #pragma unroll
  for (int m = 0; m < 2; ++m)
    #pragma unroll
    for (int n = 0; n < 8; ++n) acc[m][n] = (f32x4){0.f, 0.f, 0.f, 0.f};

  // ---- prologue: stage kt=0 into buf 0; preload A(1)
  {
    float4 x = *(const float4*)(asrc);              // A(0)
    *(half4*)(Alds[0] + awoff) = cvt4(x);
    #pragma unroll
    for (int i = 0; i < 2; ++i)
      __builtin_amdgcn_global_load_lds(
        (const __attribute__((address_space(1))) void*)(bsrc0 + i * 16384),
        (__attribute__((address_space(3))) void*)((char*)Blds[0] + tid * 16 + i * 16384),
        16, 0, 0);
  }
  float4 areg = *(const float4*)(asrc + 32);        // A(1)
  __syncthreads();

  int p = 0;
  for (int kt = 0; kt < 32; ++kt) {
    // 1) issue B(kt+1) gloads into buf p^1 (whole MFMA phase to land)
    if (kt < 31) {
      const char* bs = bsrc0 + (size_t)(kt + 1) * 32768;
      #pragma unroll
      for (int i = 0; i < 2; ++i)
        __builtin_amdgcn_global_load_lds(
          (const __attribute__((address_space(1))) void*)(bs + i * 16384),
          (__attribute__((address_space(3))) void*)((char*)Blds[p ^ 1] + tid * 16 + i * 16384),
          16, 0, 0);
    }
    // 2) A(kt+2) into regs (consumed NEXT iteration -> ~1 full kt of cover)
    const int ktn2 = (kt < 30) ? kt + 2 : 31;
    float4 anext = *(const float4*)(asrc + (size_t)ktn2 * 32);

    // 3) fragments(kt) from LDS[p]
    half8 af0 = *(const half8*)(Alds[p] + (kb * 128 + wr * 32 +      lr) * 8);
    half8 af1 = *(const half8*)(Alds[p] + (kb * 128 + wr * 32 + 16 + lr) * 8);
    const _Float16* Bp = Blds[p] + (kb * 512 + wc * 128 + lr) * 8;
    half8 bf0 = *(const half8*)(Bp);
    half8 bf1 = *(const half8*)(Bp + 16 * 8);
    half8 bf2 = *(const half8*)(Bp + 32 * 8);
    half8 bf3 = *(const half8*)(Bp + 48 * 8);

    acc[0][0] = __builtin_amdgcn_mfma_f32_16x16x32_f16(af0, bf0, acc[0][0], 0, 0, 0);
    acc[1][0] = __builtin_amdgcn_mfma_f32_16x16x32_f16(af1, bf0, acc[1][0], 0, 0, 0);
    acc[0][1] = __builtin_amdgcn_mfma_f32_16x16x32_f16(af0, bf1, acc[0][1], 0, 0, 0);
    acc[1][1] = __builtin_amdgcn_mfma_f32_16x16x32_f16(af1, bf1, acc[1][1], 0, 0, 0);
    acc[0][2] = __builtin_amdgcn_mfma_f32_16x16x32_f16(af0, bf2, acc[0][2], 0, 0, 0);
    acc[1][2] = __builtin_amdgcn_mfma_f32_16x16x32_f16(af1, bf2, acc[1][2], 0, 0, 0);
    acc[0][3] = __builtin_amdgcn_mfma_f32_16x16x32_f16(af0, bf3, acc[0][3], 0, 0, 0);
    acc[1][3] = __builtin_amdgcn_mfma_f32_16x16x32_f16(af1, bf3, acc[1][3], 0, 0, 0);

    half8 bf4 = *(const half8*)(Bp + 64 * 8);
    half8 bf5 = *(const half8*)(Bp + 80 * 8);
    half8 bf6 = *(const half8*)(Bp + 96 * 8);
    half8 bf7 = *(const half8*)(Bp + 112 * 8);
    acc[0][4] = __builtin_amdgcn_mfma_f32_16x16x32_f16(af0, bf4, acc[0][4], 0, 0, 0);
    acc[1][4] = __builtin_amdgcn_mfma_f32_16x16x32_f16(af1, bf4, acc[1][4], 0, 0, 0);
    acc[0][5] = __builtin_amdgcn_mfma_f32_16x16x32_f16(af0, bf5, acc[0][5], 0, 0, 0);
    acc[1][5] = __builtin_amdgcn_mfma_f32_16x16x32_f16(af1, bf5, acc[1][5], 0, 0, 0);
    acc[0][6] = __builtin_amdgcn_mfma_f32_16x16x32_f16(af0, bf6, acc[0][6], 0, 0, 0);
    acc[1][6] = __builtin_amdgcn_mfma_f32_16x16x32_f16(af1, bf6, acc[1][6], 0, 0, 0);
    acc[0][7] = __builtin_amdgcn_mfma_f32_16x16x32_f16(af0, bf7, acc[0][7], 0, 0, 0);
    acc[1][7] = __builtin_amdgcn_mfma_f32_16x16x32_f16(af1, bf7, acc[1][7], 0, 0, 0);

    // 4) write A(kt+1) (loaded LAST iteration) into buf p^1  [packed cvt]
    if (kt < 31) {
      *(half4*)(Alds[p ^ 1] + awoff) = cvt4(areg);
    }
    __syncthreads();
    p ^= 1;
    areg = anext;
  }

  // ---------------- epilogue (R8-verified) ----------------
  // C/D: col = lane&15, frag row = kb*4 + j ; global row = wr*32 + m*16 + kb*4 + j
  float sp[2][4];
  #pragma unroll
  for (int m = 0; m < 2; ++m)
    #pragma unroll
    for (int j = 0; j < 4; ++j) sp[m][j] = 0.f;

  #pragma unroll
  for (int n = 0; n < 8; ++n) {
    int col = wc * 128 + n * 16 + lr;
    float wan = wa_s[col], pqn = pq_s[col];
    #pragma unroll
    for (int m = 0; m < 2; ++m)
      #pragma unroll
      for (int j = 0; j < 4; ++j)
        sp[m][j] += fast_tanh(acc[m][n][j] + pqn) * wan;
  }
  #pragma unroll
  for (int m = 0; m < 2; ++m)
    #pragma unroll
    for (int j = 0; j < 4; ++j) {
      float v = sp[m][j];
      v += __shfl_xor(v, 1);
      v += __shfl_xor(v, 2);
      v += __shfl_xor(v, 4);
      v += __shfl_xor(v, 8);
      sp[m][j] = v;                    // reduced over this wave's 16-col group
    }
  if (lr == 0) {
    #pragma unroll
    for (int m = 0; m < 2; ++m)
      #pragma unroll
      for (int j = 0; j < 4; ++j)
        sc4[wr * 32 + m * 16 + kb * 4 + j][wc] = sp[m][j];
  }
  __syncthreads();

  // row scores (128 rows handled by waves 0 and 1), two-level max/sum
  const int pi = b * 16 + ch;
  float s = 0.f, pe = 0.f;
  if (tid < 128) {
    s = sc4[tid][0] + sc4[tid][1] + sc4[tid][2] + sc4[tid][3];
    float mx = s;
    #pragma unroll
    for (int off = 1; off < 64; off <<= 1) mx = fmaxf(mx, __shfl_xor(mx, off));
    if (l == 0) red2[w] = mx;
  }
  __syncthreads();
  float Mx = fmaxf(red2[0], red2[1]);
  if (tid < 128) {
    pe = __expf(s - Mx);
    pbuf[tid] = pe;
    float ls = pe;
    #pragma unroll
    for (int off = 1; off < 64; off <<= 1) ls += __shfl_xor(ls, off);
    if (l == 0) red2[4 + w] = ls;
  }
  __syncthreads();
  if (tid == 0) { mpart[pi] = Mx; lpart[pi] = red2[4] + red2[5]; }

  // ctx partial: sum_s p[s] * proj[s][col]
  float cv[8];
  #pragma unroll
  for (int n = 0; n < 8; ++n) cv[n] = 0.f;
  #pragma unroll
  for (int m = 0; m < 2; ++m)
    #pragma unroll
    for (int j = 0; j < 4; ++j) {
      float pw = pbuf[wr * 32 + m * 16 + kb * 4 + j];
      #pragma unroll
      for (int n = 0; n < 8; ++n) cv[n] += pw * acc[m][n][j];
    }
  #pragma unroll
  for (int n = 0; n < 8; ++n) {
    float v = cv[n];
    v += __shfl_xor(v, 16);
    v += __shfl_xor(v, 32);
    cv[n] = v;                         // sum over this wave's 32 rows
  }
  if (l < 16) {
    #pragma unroll
    for (int n = 0; n < 8; ++n) ctx2[wr][wc * 128 + n * 16 + l] = cv[n];
  }
  __syncthreads();

  if (tid < 512)
    ctxp[(size_t)pi * 512 + tid] =
        ctx2[0][tid] + ctx2[1][tid] + ctx2[2][tid] + ctx2[3][tid];
}

// ---- merge 16 chunk partials per batch (flash-style combine)
__global__ void k_comb(const float* __restrict__ mpart, const float* __restrict__ lpart,
                       const float* __restrict__ ctxp, float* __restrict__ out) {
  int b = blockIdx.x, a = threadIdx.x;
  float Mg = -1e30f;
  #pragma unroll
  for (int i = 0; i < 16; ++i) Mg = fmaxf(Mg, mpart[b * 16 + i]);
  float den = 0.f, s = 0.f;
  #pragma unroll
  for (int i = 0; i < 16; ++i) {
    float e = __expf(mpart[b * 16 + i] - Mg);
    den += lpart[b * 16 + i] * e;
    s   += ctxp[((size_t)(b * 16 + i)) * 512 + a] * e;
  }
  out[(size_t)b * 512 + a] = s / den;
}

extern "C" void kernel_launch(void* const* d_in, const int* in_sizes, int n_in,
                              void* d_out, int out_size, void* d_ws, size_t ws_size,
                              hipStream_t stream) {
  const float* inputs = (const float*)d_in[0];
  const float* query  = (const float*)d_in[1];
  const float* W_in   = (const float*)d_in[2];
  const float* W_q    = (const float*)d_in[3];
  const float* w_att  = (const float*)d_in[4];
  float* out = (float*)d_out;

  char* ws = (char*)d_ws;
  float*    projq = (float*)(ws + WS_PROJQ);
  float*    mpart = (float*)(ws + WS_MPART);
  float*    lpart = (float*)(ws + WS_LPART);
  float*    ctxp  = (float*)(ws + WS_CTXP);
  _Float16* wws   = (_Float16*)(ws + WS_WWS);

  k_convw<<<256, 256, 0, stream>>>(W_in, wws);
  k_projq<<<dim3(8, 32), 256, 0, stream>>>(query, W_q, projq);
  k_main<<<dim3(16, 32), 1024, 0, stream>>>(inputs, wws, projq, w_att, mpart, lpart, ctxp);
  k_comb<<<32, 512, 0, stream>>>(mpart, lpart, ctxp, out);
}

// Round 17
// 136.161 us; speedup vs baseline: 1.2910x; 1.0075x over previous
//
#include <hip/hip_runtime.h>
#include <hip/hip_fp16.h>
#include <cstdint>
#include <cstddef>

#define Bb 32
#define Ss 2048
#define Ee 1024
#define Qq 1024
#define Aa 512

typedef _Float16 half8 __attribute__((ext_vector_type(8)));
typedef _Float16 half4 __attribute__((ext_vector_type(4)));
typedef __fp16 fp16x2 __attribute__((ext_vector_type(2)));
typedef float f32x4 __attribute__((ext_vector_type(4)));

// ---- workspace byte offsets ----
#define WS_PROJQ 0u          // 32*512 f32      = 65536 B
#define WS_MPART 65536u      // 32*16 f32       = 2048 B
#define WS_LPART 67584u      // 32*16 f32       = 2048 B
#define WS_CTXP  69632u      // 32*16*512 f32   = 1048576 B
#define WS_WWS   1118208u    // 1024*512 f16    = 1048576 B

__device__ __forceinline__ float fast_tanh(float x) {
  float e = __expf(2.0f * x);
  return 1.0f - __fdividef(2.0f, e + 1.0f);
}

// packed f32x2 -> f16x2 convert
__device__ __forceinline__ half4 cvt4(float4 x) {
  fp16x2 lo = __builtin_amdgcn_cvt_pkrtz(x.x, x.y);
  fp16x2 hi = __builtin_amdgcn_cvt_pkrtz(x.z, x.w);
  half4 r;
  r[0] = (_Float16)lo[0]; r[1] = (_Float16)lo[1];
  r[2] = (_Float16)hi[0]; r[3] = (_Float16)hi[1];
  return r;
}

// ---- merged prep: blocks 0..255 convert W_in -> fp16 tiled; blocks 256..511 proj_q
__global__ void k_prep(const float* __restrict__ win, _Float16* __restrict__ wws,
                       const float* __restrict__ query, const float* __restrict__ wq,
                       float* __restrict__ projq) {
  if (blockIdx.x < 256) {
    int gid = blockIdx.x * 256 + threadIdx.x;
    int a  = gid & 511;
    int ks = (gid >> 9) & 3;
    int kt = gid >> 11;
    int k0 = kt * 32 + ks * 8;
    half8 v;
    #pragma unroll
    for (int j = 0; j < 8; ++j) v[j] = (_Float16)win[(size_t)(k0 + j) * Aa + a];
    *(half8*)(wws + ((size_t)kt * 16384 + (size_t)ks * 4096 + (size_t)a * 8)) = v;
  } else {
    __shared__ float red[256];
    int pb = blockIdx.x - 256;       // 0..255
    int b  = pb >> 3;
    int ax = pb & 7;
    int al = threadIdx.x & 63;
    int eq = threadIdx.x >> 6;
    int a  = ax * 64 + al;
    const float* q = query + (size_t)b * Qq;
    float s = 0.f;
    int e0 = eq * 256;
    #pragma unroll 4
    for (int e = e0; e < e0 + 256; ++e)
      s += q[e] * wq[(size_t)e * Aa + a];
    red[threadIdx.x] = s;
    __syncthreads();
    if (eq == 0)
      projq[(size_t)b * Aa + a] = red[al] + red[al + 64] + red[al + 128] + red[al + 192];
  }
}

// ---- main: BM=128 x BN=512, BK=32, 1024 thr, 16 waves as 2wr x 8wc.
// Wave owns 64 rows x 64 cols -> 4 A-frag + 4 B-frag ds_reads per kt (vs 10 in
// the 4x4 geometry): -20% LDS-read traffic, same 16 MFMA / 64 acc regs.
__global__ __launch_bounds__(1024, 4)
void k_main(const float* __restrict__ inp, const _Float16* __restrict__ wws,
            const float* __restrict__ projq, const float* __restrict__ watt,
            float* __restrict__ mpart, float* __restrict__ lpart,
            float* __restrict__ ctxp)
{
  __shared__ __align__(16) _Float16 Alds[2][4 * 128 * 8];   // [p][ks][row128][8] 2x8KB
  __shared__ __align__(16) _Float16 Blds[2][4 * 512 * 8];   // [p][ks][a][8]      2x32KB
  __shared__ float pq_s[512];
  __shared__ float wa_s[512];
  __shared__ float sc8[128][8];
  __shared__ float pbuf[128];
  __shared__ float red2[8];
  __shared__ float ctx2[2][512];

  const int tid = threadIdx.x;
  const int l   = tid & 63;
  const int w   = tid >> 6;        // wave 0..15
  const int lr  = l & 15;
  const int kb  = l >> 4;          // k-slot 0..3
  const int wr  = w >> 3;          // m-half 0..1 (rows wr*64 .. +63)
  const int wc  = w & 7;           // n-slice 0..7 (cols wc*64 .. +63)
  const int b   = blockIdx.y;
  const int ch  = blockIdx.x;      // s-chunk of 128 rows, 0..15

  if (tid < 512) {
    pq_s[tid] = projq[(size_t)b * Aa + tid];
    wa_s[tid] = watt[tid];
  }

  // A staging: thread t -> row = t>>3 (0..127), kq = t&7 (float4 group)
  const int arow = tid >> 3;
  const int kq   = tid & 7;
  const float* asrc = inp + ((size_t)(b * Ss + ch * 128 + arow)) * Ee + kq * 4;
  const int awoff = ((kq >> 1) * 128 + arow) * 8 + (kq & 1) * 4;   // f16 elem offset

  // B staging: 2 x 16B per thread, linear (tid*16 + i*16384 covers 32KB/kt)
  const char* bsrc0 = (const char*)wws + (size_t)tid * 16;

  f32x4 acc[4][4];
  #pragma unroll
  for (int m = 0; m < 4; ++m)
    #pragma unroll
    for (int n = 0; n < 4; ++n) acc[m][n] = (f32x4){0.f, 0.f, 0.f, 0.f};

  // ---- prologue: stage kt=0 into buf 0; preload A(1)
  {
    float4 x = *(const float4*)(asrc);              // A(0)
    *(half4*)(Alds[0] + awoff) = cvt4(x);
    #pragma unroll
    for (int i = 0; i < 2; ++i)
      __builtin_amdgcn_global_load_lds(
        (const __attribute__((address_space(1))) void*)(bsrc0 + i * 16384),
        (__attribute__((address_space(3))) void*)((char*)Blds[0] + tid * 16 + i * 16384),
        16, 0, 0);
  }
  float4 areg = *(const float4*)(asrc + 32);        // A(1)
  __syncthreads();

  int p = 0;
  for (int kt = 0; kt < 32; ++kt) {
    // 1) issue B(kt+1) gloads into buf p^1 (whole MFMA phase to land)
    if (kt < 31) {
      const char* bs = bsrc0 + (size_t)(kt + 1) * 32768;
      #pragma unroll
      for (int i = 0; i < 2; ++i)
        __builtin_amdgcn_global_load_lds(
          (const __attribute__((address_space(1))) void*)(bs + i * 16384),
          (__attribute__((address_space(3))) void*)((char*)Blds[p ^ 1] + tid * 16 + i * 16384),
          16, 0, 0);
    }
    // 2) A(kt+2) into regs (consumed NEXT iteration)
    const int ktn2 = (kt < 30) ? kt + 2 : 31;
    float4 anext = *(const float4*)(asrc + (size_t)ktn2 * 32);

    // 3) fragments(kt) from LDS[p]: 4 A + 4 B reads (vs 2+8 before)
    half8 af0 = *(const half8*)(Alds[p] + (kb * 128 + wr * 64 +      lr) * 8);
    half8 af1 = *(const half8*)(Alds[p] + (kb * 128 + wr * 64 + 16 + lr) * 8);
    half8 af2 = *(const half8*)(Alds[p] + (kb * 128 + wr * 64 + 32 + lr) * 8);
    half8 af3 = *(const half8*)(Alds[p] + (kb * 128 + wr * 64 + 48 + lr) * 8);
    const _Float16* Bp = Blds[p] + (kb * 512 + wc * 64 + lr) * 8;
    half8 bf0 = *(const half8*)(Bp);
    half8 bf1 = *(const half8*)(Bp + 16 * 8);
    half8 bf2 = *(const half8*)(Bp + 32 * 8);
    half8 bf3 = *(const half8*)(Bp + 48 * 8);

    acc[0][0] = __builtin_amdgcn_mfma_f32_16x16x32_f16(af0, bf0, acc[0][0], 0, 0, 0);
    acc[0][1] = __builtin_amdgcn_mfma_f32_16x16x32_f16(af0, bf1, acc[0][1], 0, 0, 0);
    acc[0][2] = __builtin_amdgcn_mfma_f32_16x16x32_f16(af0, bf2, acc[0][2], 0, 0, 0);
    acc[0][3] = __builtin_amdgcn_mfma_f32_16x16x32_f16(af0, bf3, acc[0][3], 0, 0, 0);
    acc[1][0] = __builtin_amdgcn_mfma_f32_16x16x32_f16(af1, bf0, acc[1][0], 0, 0, 0);
    acc[1][1] = __builtin_amdgcn_mfma_f32_16x16x32_f16(af1, bf1, acc[1][1], 0, 0, 0);
    acc[1][2] = __builtin_amdgcn_mfma_f32_16x16x32_f16(af1, bf2, acc[1][2], 0, 0, 0);
    acc[1][3] = __builtin_amdgcn_mfma_f32_16x16x32_f16(af1, bf3, acc[1][3], 0, 0, 0);
    acc[2][0] = __builtin_amdgcn_mfma_f32_16x16x32_f16(af2, bf0, acc[2][0], 0, 0, 0);
    acc[2][1] = __builtin_amdgcn_mfma_f32_16x16x32_f16(af2, bf1, acc[2][1], 0, 0, 0);
    acc[2][2] = __builtin_amdgcn_mfma_f32_16x16x32_f16(af2, bf2, acc[2][2], 0, 0, 0);
    acc[2][3] = __builtin_amdgcn_mfma_f32_16x16x32_f16(af2, bf3, acc[2][3], 0, 0, 0);
    acc[3][0] = __builtin_amdgcn_mfma_f32_16x16x32_f16(af3, bf0, acc[3][0], 0, 0, 0);
    acc[3][1] = __builtin_amdgcn_mfma_f32_16x16x32_f16(af3, bf1, acc[3][1], 0, 0, 0);
    acc[3][2] = __builtin_amdgcn_mfma_f32_16x16x32_f16(af3, bf2, acc[3][2], 0, 0, 0);
    acc[3][3] = __builtin_amdgcn_mfma_f32_16x16x32_f16(af3, bf3, acc[3][3], 0, 0, 0);

    // 4) write A(kt+1) (loaded LAST iteration) into buf p^1
    if (kt < 31) {
      *(half4*)(Alds[p ^ 1] + awoff) = cvt4(areg);
    }
    __syncthreads();
    p ^= 1;
    areg = anext;
  }

  // ---------------- epilogue ----------------
  // C/D: col = lane&15, frag row = kb*4 + j
  // global row = wr*64 + m*16 + kb*4 + j ; global col = wc*64 + n*16 + lr
  float sp[4][4];
  #pragma unroll
  for (int m = 0; m < 4; ++m)
    #pragma unroll
    for (int j = 0; j < 4; ++j) sp[m][j] = 0.f;

  #pragma unroll
  for (int n = 0; n < 4; ++n) {
    int col = wc * 64 + n * 16 + lr;
    float wan = wa_s[col], pqn = pq_s[col];
    #pragma unroll
    for (int m = 0; m < 4; ++m)
      #pragma unroll
      for (int j = 0; j < 4; ++j)
        sp[m][j] += fast_tanh(acc[m][n][j] + pqn) * wan;
  }
  #pragma unroll
  for (int m = 0; m < 4; ++m)
    #pragma unroll
    for (int j = 0; j < 4; ++j) {
      float v = sp[m][j];
      v += __shfl_xor(v, 1);
      v += __shfl_xor(v, 2);
      v += __shfl_xor(v, 4);
      v += __shfl_xor(v, 8);
      sp[m][j] = v;                    // reduced over this wave's 16-col group
    }
  if (lr == 0) {
    #pragma unroll
    for (int m = 0; m < 4; ++m)
      #pragma unroll
      for (int j = 0; j < 4; ++j)
        sc8[wr * 64 + m * 16 + kb * 4 + j][wc] = sp[m][j];
  }
  __syncthreads();

  // row scores (128 rows on waves 0-1), two-level max/sum
  const int pi = b * 16 + ch;
  float s = 0.f, pe = 0.f;
  if (tid < 128) {
    s = sc8[tid][0] + sc8[tid][1] + sc8[tid][2] + sc8[tid][3]
      + sc8[tid][4] + sc8[tid][5] + sc8[tid][6] + sc8[tid][7];
    float mx = s;
    #pragma unroll
    for (int off = 1; off < 64; off <<= 1) mx = fmaxf(mx, __shfl_xor(mx, off));
    if (l == 0) red2[w] = mx;
  }
  __syncthreads();
  float Mx = fmaxf(red2[0], red2[1]);
  if (tid < 128) {
    pe = __expf(s - Mx);
    pbuf[tid] = pe;
    float ls = pe;
    #pragma unroll
    for (int off = 1; off < 64; off <<= 1) ls += __shfl_xor(ls, off);
    if (l == 0) red2[4 + w] = ls;
  }
  __syncthreads();
  if (tid == 0) { mpart[pi] = Mx; lpart[pi] = red2[4] + red2[5]; }

  // ctx partial: cv[n] = sum over this wave's 64 rows of p[row]*proj[row][col]
  float cv[4];
  #pragma unroll
  for (int n = 0; n < 4; ++n) cv[n] = 0.f;
  #pragma unroll
  for (int m = 0; m < 4; ++m)
    #pragma unroll
    for (int j = 0; j < 4; ++j) {
      float pw = pbuf[wr * 64 + m * 16 + kb * 4 + j];
      #pragma unroll
      for (int n = 0; n < 4; ++n) cv[n] += pw * acc[m][n][j];
    }
  #pragma unroll
  for (int n = 0; n < 4; ++n) {
    float v = cv[n];
    v += __shfl_xor(v, 16);
    v += __shfl_xor(v, 32);
    cv[n] = v;                         // summed over kb-groups -> all 64 rows
  }
  if (l < 16) {
    #pragma unroll
    for (int n = 0; n < 4; ++n) ctx2[wr][wc * 64 + n * 16 + l] = cv[n];
  }
  __syncthreads();

  if (tid < 512)
    ctxp[(size_t)pi * 512 + tid] = ctx2[0][tid] + ctx2[1][tid];
}

// ---- merge 16 chunk partials per batch (flash-style combine)
__global__ void k_comb(const float* __restrict__ mpart, const float* __restrict__ lpart,
                       const float* __restrict__ ctxp, float* __restrict__ out) {
  int b = blockIdx.x, a = threadIdx.x;
  float Mg = -1e30f;
  #pragma unroll
  for (int i = 0; i < 16; ++i) Mg = fmaxf(Mg, mpart[b * 16 + i]);
  float den = 0.f, s = 0.f;
  #pragma unroll
  for (int i = 0; i < 16; ++i) {
    float e = __expf(mpart[b * 16 + i] - Mg);
    den += lpart[b * 16 + i] * e;
    s   += ctxp[((size_t)(b * 16 + i)) * 512 + a] * e;
  }
  out[(size_t)b * 512 + a] = s / den;
}

extern "C" void kernel_launch(void* const* d_in, const int* in_sizes, int n_in,
                              void* d_out, int out_size, void* d_ws, size_t ws_size,
                              hipStream_t stream) {
  const float* inputs = (const float*)d_in[0];
  const float* query  = (const float*)d_in[1];
  const float* W_in   = (const float*)d_in[2];
  const float* W_q    = (const float*)d_in[3];
  const float* w_att  = (const float*)d_in[4];
  float* out = (float*)d_out;

  char* ws = (char*)d_ws;
  float*    projq = (float*)(ws + WS_PROJQ);
  float*    mpart = (float*)(ws + WS_MPART);
  float*    lpart = (float*)(ws + WS_LPART);
  float*    ctxp  = (float*)(ws + WS_CTXP);
  _Float16* wws   = (_Float16*)(ws + WS_WWS);

  k_prep<<<512, 256, 0, stream>>>(W_in, wws, query, W_q, projq);
  k_main<<<dim3(16, 32), 1024, 0, stream>>>(inputs, wws, projq, w_att, mpart, lpart, ctxp);
  k_comb<<<32, 512, 0, stream>>>(mpart, lpart, ctxp, out);
}